// Round 6
// baseline (818.866 us; speedup 1.0000x reference)
//
#include <hip/hip_runtime.h>

#define SEQ 550
#define MID 100
#define TPB 64

typedef _Float16 half2_t __attribute__((ext_vector_type(2)));
typedef _Float16 half8_t __attribute__((ext_vector_type(8)));
typedef __fp16  fp16x2  __attribute__((ext_vector_type(2)));
typedef float f32x4 __attribute__((ext_vector_type(4)));

union H2I { int i; half2_t h; };
union H8X { half8_t h8; half2_t h2[4]; int4 i4; };
union PKC { fp16x2 p; half2_t h; };

__device__ __forceinline__ float fdot2(half2_t a, half2_t b, float c) {
    return __builtin_amdgcn_fdot2(a, b, c, false);
}
__device__ __forceinline__ float sigm(float x) { return 1.0f / (1.0f + __expf(-x)); }
__device__ __forceinline__ float tanh_f(float x) { return 1.0f - 2.0f / (__expf(2.0f * x) + 1.0f); }
__device__ __forceinline__ half2_t i2h(int v) { H2I u; u.i = v; return u.h; }
__device__ __forceinline__ float pullf(int idx, float v) {
    return __int_as_float(__builtin_amdgcn_ds_bpermute(idx, __float_as_int(v)));
}
__device__ __forceinline__ half2_t pk2(float a, float b) {
    PKC u; u.p = __builtin_amdgcn_cvt_pkrtz(a, b); return u.h;
}
__device__ __forceinline__ half8_t zero8() {
    return half8_t{(_Float16)0.f, (_Float16)0.f, (_Float16)0.f, (_Float16)0.f,
                   (_Float16)0.f, (_Float16)0.f, (_Float16)0.f, (_Float16)0.f};
}

// Single wave. 19 MFMA tiles (16x16x32 f16):
//   tiles 0..5  : W_hr rows 0..95   (gate r, units 0..95)
//   tiles 6..11 : W_hz rows 100..195 (gate z)
//   tiles 12..17: W_hn rows 200..295 (gate n, hidden side only)
//   tile 18     : rows 0..3 = r units 96..99, 4..7 = z units 96..99,
//                 8..11 = n units 96..99 (hidden only), 12..15 = zero
// K: slices 0..2 = h cols 0..95 (A in AGPR); e-slice fused as chain head via
// A_ih (VGPR) for r/z tiles only (n-gate input side must stay separate).
// B = value replicated across 16 cols -> D identical across cols; 4 m==0
// lanes store quads to gates[] LDS; every lane mixes units l and 64+l.

__global__ __launch_bounds__(TPB, 1)
__attribute__((amdgpu_waves_per_eu(1, 1)))
void gru_fused(
    const int*   __restrict__ x,
    const float* __restrict__ hidden,
    const float* __restrict__ embed,
    const float* __restrict__ w_ih,
    const float* __restrict__ w_hh,
    const float* __restrict__ b_ih,
    const float* __restrict__ b_hh,
    const float* __restrict__ fc_w,
    const float* __restrict__ fc_b,
    float*       __restrict__ out)
{
    __shared__ __align__(16) int seqbuf[SEQ * 16 + 16];  // row t: halves 0..9 = e_t, rest 0
    __shared__ __align__(16) int gates[400];             // f32: [gate*100 + u]; 384.. = dump

    const int  l  = threadIdx.x;     // 0..63, single wave
    const int  m  = l & 15;
    const int  g  = l >> 4;
    const bool m0 = (m == 0);

    // ---- stage embedded sequence as fp16 (zero-padded rows of 32 halves) ----
    for (int i = l; i < SEQ * 16 + 16; i += TPB) seqbuf[i] = 0;
    for (int i = l; i < SEQ * 5; i += TPB) {
        int t = i / 5, j = i - 5 * t;
        float2 f = *(const float2*)(embed + x[t] * 10 + 2 * j);
        H2I c; c.h = half2_t{(_Float16)f.x, (_Float16)f.y};
        seqbuf[t * 16 + j] = c.i;
    }

    // ---- A_hh fragments: 19 tiles x 3 K-slices (h cols 0..95) ----
    half8_t ahh[19][3];
    #pragma unroll
    for (int tt = 0; tt < 19; tt++) {
        int row = 0; bool val = true;
        if (tt < 6)       row = tt * 16 + m;
        else if (tt < 12) row = 100 + (tt - 6) * 16 + m;
        else if (tt < 18) row = 200 + (tt - 12) * 16 + m;
        else {
            if (m < 4)       row = 96 + m;
            else if (m < 8)  row = 196 + (m - 4);
            else if (m < 12) row = 296 + (m - 8);
            else             val = false;
        }
        #pragma unroll
        for (int s = 0; s < 3; s++) {
            half8_t a = zero8();
            if (val) {
                const float* p = w_hh + row * MID + 32 * s + 8 * g;
                float4 f0 = *(const float4*)p;
                float4 f1 = *(const float4*)(p + 4);
                a = half8_t{(_Float16)f0.x, (_Float16)f0.y, (_Float16)f0.z, (_Float16)f0.w,
                            (_Float16)f1.x, (_Float16)f1.y, (_Float16)f1.z, (_Float16)f1.w};
            }
            ahh[tt][s] = a;
        }
    }

    // ---- A_ih fragments (e-slice) for r/z tiles 0..11 and tile 18 (r/z rows only) ----
    half8_t aih[13];
    #pragma unroll
    for (int q = 0; q < 13; q++) {
        int row = 0; bool val = true;
        if (q < 6)       row = q * 16 + m;
        else if (q < 12) row = 100 + (q - 6) * 16 + m;
        else {           // tile 18: e-part only for r/z leftover rows
            if (m < 4)      row = 96 + m;
            else if (m < 8) row = 196 + (m - 4);
            else            val = false;
        }
        half8_t a = zero8();
        if (val) {
            const float* p = w_ih + row * 10;
            if (g == 0) {
                float2 c0 = *(const float2*)(p);
                float2 c1 = *(const float2*)(p + 2);
                float2 c2 = *(const float2*)(p + 4);
                float2 c3 = *(const float2*)(p + 6);
                a = half8_t{(_Float16)c0.x, (_Float16)c0.y, (_Float16)c1.x, (_Float16)c1.y,
                            (_Float16)c2.x, (_Float16)c2.y, (_Float16)c3.x, (_Float16)c3.y};
            } else if (g == 1) {
                float2 c = *(const float2*)(p + 8);
                a[0] = (_Float16)c.x; a[1] = (_Float16)c.y;
            }
        }
        aih[q] = a;
    }

    // ---- pin A_hh to AGPRs, A_ih to VGPRs; opaque to kill rematerialization ----
    #pragma unroll
    for (int tt = 0; tt < 19; tt++)
        asm volatile("" : "+a"(ahh[tt][0]), "+a"(ahh[tt][1]), "+a"(ahh[tt][2]));
    #pragma unroll
    for (int q = 0; q < 13; q++)
        asm volatile("" : "+v"(aih[q]));

    // ---- per-lane mixer state: units u1 = l, u2 = 64+l (l<36) ----
    const int u1 = l;
    const int u2 = (l < 36) ? 64 + l : 99;

    half2_t w96r1[2], w96z1[2], w96n1[2], w96r2[2], w96z2[2], w96n2[2];
    {
        float4 f;
        f = *(const float4*)(w_hh + u1 * MID + 96);
        w96r1[0] = half2_t{(_Float16)f.x, (_Float16)f.y}; w96r1[1] = half2_t{(_Float16)f.z, (_Float16)f.w};
        f = *(const float4*)(w_hh + (MID + u1) * MID + 96);
        w96z1[0] = half2_t{(_Float16)f.x, (_Float16)f.y}; w96z1[1] = half2_t{(_Float16)f.z, (_Float16)f.w};
        f = *(const float4*)(w_hh + (2 * MID + u1) * MID + 96);
        w96n1[0] = half2_t{(_Float16)f.x, (_Float16)f.y}; w96n1[1] = half2_t{(_Float16)f.z, (_Float16)f.w};
        f = *(const float4*)(w_hh + u2 * MID + 96);
        w96r2[0] = half2_t{(_Float16)f.x, (_Float16)f.y}; w96r2[1] = half2_t{(_Float16)f.z, (_Float16)f.w};
        f = *(const float4*)(w_hh + (MID + u2) * MID + 96);
        w96z2[0] = half2_t{(_Float16)f.x, (_Float16)f.y}; w96z2[1] = half2_t{(_Float16)f.z, (_Float16)f.w};
        f = *(const float4*)(w_hh + (2 * MID + u2) * MID + 96);
        w96n2[0] = half2_t{(_Float16)f.x, (_Float16)f.y}; w96n2[1] = half2_t{(_Float16)f.z, (_Float16)f.w};
    }
    half2_t win1[5], win2[5];    // w_ih n-gate rows (input side of n, VALU path)
    #pragma unroll
    for (int k = 0; k < 5; k++) {
        float2 a = *(const float2*)(w_ih + (2 * MID + u1) * 10 + 2 * k);
        float2 b = *(const float2*)(w_ih + (2 * MID + u2) * 10 + 2 * k);
        win1[k] = half2_t{(_Float16)a.x, (_Float16)a.y};
        win2[k] = half2_t{(_Float16)b.x, (_Float16)b.y};
    }
    const float br1  = b_ih[u1] + b_hh[u1];
    const float bz1  = b_ih[MID + u1] + b_hh[MID + u1];
    const float bin1 = b_ih[2 * MID + u1];
    const float bhn1 = b_hh[2 * MID + u1];
    const float br2  = b_ih[u2] + b_hh[u2];
    const float bz2  = b_ih[MID + u2] + b_hh[MID + u2];
    const float bin2 = b_ih[2 * MID + u2];
    const float bhn2 = b_hh[2 * MID + u2];

    float h1 = hidden[u1];
    float h2 = hidden[u2];
    const float fw1 = fc_w[u1];
    const float fw2 = fc_w[u2];

    // bpermute byte-indices
    int idxA[8], idxB[8];
    #pragma unroll
    for (int j = 0; j < 8; j++) { idxA[j] = (8 * g + j) * 4; idxB[j] = idxA[j] + 128; }

    const f32x4 zf = {0.f, 0.f, 0.f, 0.f};
    const float* gf = (const float*)gates;
    int soff = 0;

    #pragma unroll 1
    for (int t = 0; t < SEQ; t++) {
        // e_t reads (broadcast, independent of h)
        H8X be; be.i4 = *(const int4*)(seqbuf + soff + 4 * g);
        int4 e03 = *(const int4*)(seqbuf + soff);
        int  e4w = seqbuf[soff + 4];

        // B fragments from h registers (no LDS h)
        H8X b0, b1, b2;
        #pragma unroll
        for (int j = 0; j < 4; j++) {
            b0.h2[j] = pk2(pullf(idxA[2 * j], h1), pullf(idxA[2 * j + 1], h1));
            b1.h2[j] = pk2(pullf(idxB[2 * j], h1), pullf(idxB[2 * j + 1], h1));
            b2.h2[j] = pk2(pullf(idxA[2 * j], h2), pullf(idxA[2 * j + 1], h2));
        }
        half2_t tv0 = pk2(pullf(128, h2), pullf(132, h2));  // h96,h97
        half2_t tv1 = pk2(pullf(136, h2), pullf(140, h2));  // h98,h99

        // 19 tile-chains (e-slice fused for r/z), m==0 lanes store D quads
        #pragma unroll
        for (int tt = 0; tt < 19; tt++) {
            f32x4 d;
            if (tt < 12)
                d = __builtin_amdgcn_mfma_f32_16x16x32_f16(aih[tt], be.h8, zf, 0, 0, 0);
            else if (tt == 18)
                d = __builtin_amdgcn_mfma_f32_16x16x32_f16(aih[12], be.h8, zf, 0, 0, 0);
            else
                d = zf;
            d = __builtin_amdgcn_mfma_f32_16x16x32_f16(ahh[tt][0], b0.h8, d, 0, 0, 0);
            d = __builtin_amdgcn_mfma_f32_16x16x32_f16(ahh[tt][1], b1.h8, d, 0, 0, 0);
            d = __builtin_amdgcn_mfma_f32_16x16x32_f16(ahh[tt][2], b2.h8, d, 0, 0, 0);
            if (m0) {
                int boff;
                if (tt < 6)       boff = tt * 16 + 4 * g;
                else if (tt < 12) boff = 100 + (tt - 6) * 16 + 4 * g;
                else if (tt < 18) boff = 200 + (tt - 12) * 16 + 4 * g;
                else              boff = (g == 0) ? 96 : (g == 1) ? 196 : (g == 2) ? 296 : 384;
                *(f32x4*)(gates + boff) = d;
            }
        }

        // gate reads (same-wave in-order after writes; latency hidden under tails)
        float gr1 = gf[u1], gz1 = gf[100 + u1], gn1 = gf[200 + u1];
        float gr2 = gf[u2], gz2 = gf[100 + u2], gn2 = gf[200 + u2];

        // VALU tails + mix
        half2_t ev0 = i2h(e03.x), ev1 = i2h(e03.y), ev2 = i2h(e03.z), ev3 = i2h(e03.w), ev4 = i2h(e4w);

        float ar1 = br1;  ar1 = fdot2(w96r1[0], tv0, ar1); ar1 = fdot2(w96r1[1], tv1, ar1); ar1 += gr1;
        float az1 = bz1;  az1 = fdot2(w96z1[0], tv0, az1); az1 = fdot2(w96z1[1], tv1, az1); az1 += gz1;
        float gh1 = bhn1; gh1 = fdot2(w96n1[0], tv0, gh1); gh1 = fdot2(w96n1[1], tv1, gh1); gh1 += gn1;
        float gi1 = bin1;
        gi1 = fdot2(win1[0], ev0, gi1); gi1 = fdot2(win1[1], ev1, gi1); gi1 = fdot2(win1[2], ev2, gi1);
        gi1 = fdot2(win1[3], ev3, gi1); gi1 = fdot2(win1[4], ev4, gi1);

        float ar2 = br2;  ar2 = fdot2(w96r2[0], tv0, ar2); ar2 = fdot2(w96r2[1], tv1, ar2); ar2 += gr2;
        float az2 = bz2;  az2 = fdot2(w96z2[0], tv0, az2); az2 = fdot2(w96z2[1], tv1, az2); az2 += gz2;
        float gh2 = bhn2; gh2 = fdot2(w96n2[0], tv0, gh2); gh2 = fdot2(w96n2[1], tv1, gh2); gh2 += gn2;
        float gi2 = bin2;
        gi2 = fdot2(win2[0], ev0, gi2); gi2 = fdot2(win2[1], ev1, gi2); gi2 = fdot2(win2[2], ev2, gi2);
        gi2 = fdot2(win2[3], ev3, gi2); gi2 = fdot2(win2[4], ev4, gi2);

        float r1 = sigm(ar1), z1 = sigm(az1);
        float n1 = tanh_f(gi1 + r1 * gh1);
        h1 = n1 + z1 * (h1 - n1);

        float r2 = sigm(ar2), z2 = sigm(az2);
        float n2 = tanh_f(gi2 + r2 * gh2);
        float h2n = n2 + z2 * (h2 - n2);
        h2 = (l < 36) ? h2n : h2;

        soff += 16;
    }

    // ---- epilogue: sigmoid(relu(h) . fc_w + fc_b) ----
    float acc = fmaxf(h1, 0.f) * fw1 + ((l < 36) ? fmaxf(h2, 0.f) * fw2 : 0.f);
    #pragma unroll
    for (int k = 32; k >= 1; k >>= 1) acc += __shfl_xor(acc, k, 64);
    if (l == 0) out[0] = sigm(acc + fc_b[0]);
}

extern "C" void kernel_launch(void* const* d_in, const int* in_sizes, int n_in,
                              void* d_out, int out_size, void* d_ws, size_t ws_size,
                              hipStream_t stream) {
    const int*   x      = (const int*)  d_in[0];
    const float* hidden = (const float*)d_in[1];
    const float* embed  = (const float*)d_in[2];
    const float* w_ih   = (const float*)d_in[3];
    const float* w_hh   = (const float*)d_in[4];
    const float* b_ih   = (const float*)d_in[5];
    const float* b_hh   = (const float*)d_in[6];
    const float* fc_w   = (const float*)d_in[7];
    const float* fc_b   = (const float*)d_in[8];
    float*       out    = (float*)d_out;

    gru_fused<<<1, TPB, 0, stream>>>(x, hidden, embed, w_ih, w_hh,
                                     b_ih, b_hh, fc_w, fc_b, out);
}

// Round 7
// 614.596 us; speedup vs baseline: 1.3324x; 1.3324x over previous
//
#include <hip/hip_runtime.h>

#define SEQ 550
#define MID 100
#define TPB 128

typedef _Float16 half2_t __attribute__((ext_vector_type(2)));
typedef _Float16 half8_t __attribute__((ext_vector_type(8)));
typedef __fp16  fp16x2  __attribute__((ext_vector_type(2)));
typedef float f32x4 __attribute__((ext_vector_type(4)));

union H2I { int i; half2_t h; };
union H8X { half8_t h8; half2_t h2[4]; int4 i4; };
union PKC { fp16x2 p; half2_t h; };

__device__ __forceinline__ float fdot2(half2_t a, half2_t b, float c) {
    return __builtin_amdgcn_fdot2(a, b, c, false);
}
__device__ __forceinline__ float sigm(float x) { return 1.0f / (1.0f + __expf(-x)); }
__device__ __forceinline__ float tanh_f(float x) { return 1.0f - 2.0f / (__expf(2.0f * x) + 1.0f); }
__device__ __forceinline__ half2_t i2h(int v) { H2I u; u.i = v; return u.h; }
__device__ __forceinline__ float pullf(int idx, float v) {
    return __int_as_float(__builtin_amdgcn_ds_bpermute(idx, __float_as_int(v)));
}
__device__ __forceinline__ half2_t pk2(float a, float b) {
    PKC u; u.p = __builtin_amdgcn_cvt_pkrtz(a, b); return u.h;
}
__device__ __forceinline__ half8_t zero8() {
    return half8_t{(_Float16)0.f, (_Float16)0.f, (_Float16)0.f, (_Float16)0.f,
                   (_Float16)0.f, (_Float16)0.f, (_Float16)0.f, (_Float16)0.f};
}

// 2 waves. 20 tile slots (16x16x32 f16), wave w owns tiles T = 10w..10w+9:
//   T 0..5  : W_hr rows 0..95 (gate r)     T 6..11 : W_hz (gate z)
//   T 12..17: W_hn (gate n, hidden side)   T 18    : leftover units 96..99 (r,z,n)
//   T 19    : dummy (zero A, dump store)
// K slices 0..2 = h cols 0..95. B = h replicated across cols (validated r4) ->
// D identical across cols; m==0 lanes store quads into ping-pong gates[].
// One __syncthreads per step. Each wave holds the FULL h state in registers
// (units l and 64+l per lane) and mixes redundantly; B built via ds_bpermute.

__global__ __launch_bounds__(TPB, 1) void gru_fused(
    const int*   __restrict__ x,
    const float* __restrict__ hidden,
    const float* __restrict__ embed,
    const float* __restrict__ w_ih,
    const float* __restrict__ w_hh,
    const float* __restrict__ b_ih,
    const float* __restrict__ b_hh,
    const float* __restrict__ fc_w,
    const float* __restrict__ fc_b,
    float*       __restrict__ out)
{
    __shared__ __align__(16) int seqbuf[SEQ * 8];   // e_t: 5 packed half2 + pad
    __shared__ __align__(16) int gates[2][416];     // ping-pong; f32 [gate*100+u]; 408=dump

    const int  tid = threadIdx.x;
    const int  w   = tid >> 6;
    const int  l   = tid & 63;
    const int  m   = l & 15;
    const int  g   = l >> 4;
    const bool m0  = (m == 0);

    // ---- stage embedded sequence as fp16 ----
    for (int i = tid; i < SEQ * 5; i += TPB) {
        int t = i / 5, j = i - 5 * t;
        float2 f = *(const float2*)(embed + x[t] * 10 + 2 * j);
        H2I c; c.h = half2_t{(_Float16)f.x, (_Float16)f.y};
        seqbuf[t * 8 + j] = c.i;
    }

    // ---- A fragments: 10 tiles x 3 K-slices per wave (h cols 0..95) ----
    half8_t afr[10][3];
    int     boffs[10];
    #pragma unroll
    for (int tt = 0; tt < 10; tt++) {
        const int T = 10 * w + tt;
        int row = 0; bool val = true;
        if (T < 6)       row = T * 16 + m;
        else if (T < 12) row = 100 + (T - 6) * 16 + m;
        else if (T < 18) row = 200 + (T - 12) * 16 + m;
        else if (T == 18) {
            if (m < 4)       row = 96 + m;
            else if (m < 8)  row = 196 + (m - 4);
            else if (m < 12) row = 296 + (m - 8);
            else             val = false;
        } else val = false;        // T==19 dummy
        #pragma unroll
        for (int s = 0; s < 3; s++) {
            half8_t a = zero8();
            if (val) {
                const float* p = w_hh + row * MID + 32 * s + 8 * g;
                float4 f0 = *(const float4*)p;
                float4 f1 = *(const float4*)(p + 4);
                a = half8_t{(_Float16)f0.x, (_Float16)f0.y, (_Float16)f0.z, (_Float16)f0.w,
                            (_Float16)f1.x, (_Float16)f1.y, (_Float16)f1.z, (_Float16)f1.w};
            }
            afr[tt][s] = a;
        }
        int bo;
        if (T < 6)        bo = T * 16 + 4 * g;
        else if (T < 12)  bo = 100 + (T - 6) * 16 + 4 * g;
        else if (T < 18)  bo = 200 + (T - 12) * 16 + 4 * g;
        else if (T == 18) bo = (g == 0) ? 96 : (g == 1) ? 196 : (g == 2) ? 296 : 408;
        else              bo = 408;
        boffs[tt] = bo;
    }
    // pin fragments in VGPRs (defeat rematerialization; fits: ~120 regs)
    #pragma unroll
    for (int tt = 0; tt < 10; tt++)
        asm volatile("" : "+v"(afr[tt][0]), "+v"(afr[tt][1]), "+v"(afr[tt][2]));

    // ---- per-lane mixer state: units uA = l, uB = 64+l (valid l<36) ----
    const int uA = l;
    const int uB = (l < 36) ? 64 + l : 99;

    half2_t wiA[3][5], wiB[3][5];   // w_ih rows (input side, VALU)
    half2_t w96A[3][2], w96B[3][2]; // w_hh cols 96..99 (tail, VALU)
    #pragma unroll
    for (int r = 0; r < 3; r++) {
        const float* ia = w_ih + (r * MID + uA) * 10;
        const float* ib = w_ih + (r * MID + uB) * 10;
        #pragma unroll
        for (int k = 0; k < 5; k++) {
            float2 fa = *(const float2*)(ia + 2 * k);
            float2 fb = *(const float2*)(ib + 2 * k);
            wiA[r][k] = half2_t{(_Float16)fa.x, (_Float16)fa.y};
            wiB[r][k] = half2_t{(_Float16)fb.x, (_Float16)fb.y};
        }
        float4 ha = *(const float4*)(w_hh + (r * MID + uA) * MID + 96);
        float4 hb = *(const float4*)(w_hh + (r * MID + uB) * MID + 96);
        w96A[r][0] = half2_t{(_Float16)ha.x, (_Float16)ha.y};
        w96A[r][1] = half2_t{(_Float16)ha.z, (_Float16)ha.w};
        w96B[r][0] = half2_t{(_Float16)hb.x, (_Float16)hb.y};
        w96B[r][1] = half2_t{(_Float16)hb.z, (_Float16)hb.w};
    }
    const float brA  = b_ih[uA] + b_hh[uA];
    const float bzA  = b_ih[MID + uA] + b_hh[MID + uA];
    const float binA = b_ih[2 * MID + uA];
    const float bhnA = b_hh[2 * MID + uA];
    const float brB  = b_ih[uB] + b_hh[uB];
    const float bzB  = b_ih[MID + uB] + b_hh[MID + uB];
    const float binB = b_ih[2 * MID + uB];
    const float bhnB = b_hh[2 * MID + uB];

    float hA = hidden[uA];
    float hB = hidden[uB];
    const float fwA = fc_w[uA];
    const float fwB = fc_w[uB];

    __syncthreads();

    const f32x4 zf = {0.f, 0.f, 0.f, 0.f};

    #pragma unroll 1
    for (int t = 0; t < SEQ; t++) {
        int*         gp  = gates[t & 1];
        const float* gpf = (const float*)gp;

        // e_t (broadcast reads, independent of h)
        const int* eb = seqbuf + t * 8;
        int4 e4 = *(const int4*)eb;
        int  e1w = eb[4];
        half2_t ev0 = i2h(e4.x), ev1 = i2h(e4.y), ev2 = i2h(e4.z), ev3 = i2h(e4.w), ev4 = i2h(e1w);

        // B fragments from h registers (slice0: h[8g..], slice1: h[32+8g..], slice2: h[64+8g..])
        H8X b0, b1, b2;
        #pragma unroll
        for (int j = 0; j < 4; j++) {
            int i0 = (8 * g + 2 * j) * 4;
            b0.h2[j] = pk2(pullf(i0, hA),       pullf(i0 + 4, hA));
            b1.h2[j] = pk2(pullf(i0 + 128, hA), pullf(i0 + 132, hA));
            b2.h2[j] = pk2(pullf(i0, hB),       pullf(i0 + 4, hB));
        }
        // h96..99 (from hB of lanes 32..35)
        half2_t tv0 = pk2(pullf(128, hB), pullf(132, hB));
        half2_t tv1 = pk2(pullf(136, hB), pullf(140, hB));

        // MFMA: 10 tile-chains; m==0 lanes store D quads to ping-pong gates
        #pragma unroll
        for (int tt = 0; tt < 10; tt++) {
            f32x4 d = __builtin_amdgcn_mfma_f32_16x16x32_f16(afr[tt][0], b0.h8, zf, 0, 0, 0);
            d = __builtin_amdgcn_mfma_f32_16x16x32_f16(afr[tt][1], b1.h8, d, 0, 0, 0);
            d = __builtin_amdgcn_mfma_f32_16x16x32_f16(afr[tt][2], b2.h8, d, 0, 0, 0);
            if (m0) *(f32x4*)(gp + boffs[tt]) = d;
        }

        // VALU side-work (co-issues under MFMA): input dots + col-96..99 tails
        float arA = brA, azA = bzA, giA = binA, ghA = bhnA;
        float arB = brB, azB = bzB, giB = binB, ghB = bhnB;
        arA = fdot2(wiA[0][0], ev0, arA); arA = fdot2(wiA[0][1], ev1, arA);
        arA = fdot2(wiA[0][2], ev2, arA); arA = fdot2(wiA[0][3], ev3, arA);
        arA = fdot2(wiA[0][4], ev4, arA);
        azA = fdot2(wiA[1][0], ev0, azA); azA = fdot2(wiA[1][1], ev1, azA);
        azA = fdot2(wiA[1][2], ev2, azA); azA = fdot2(wiA[1][3], ev3, azA);
        azA = fdot2(wiA[1][4], ev4, azA);
        giA = fdot2(wiA[2][0], ev0, giA); giA = fdot2(wiA[2][1], ev1, giA);
        giA = fdot2(wiA[2][2], ev2, giA); giA = fdot2(wiA[2][3], ev3, giA);
        giA = fdot2(wiA[2][4], ev4, giA);
        arB = fdot2(wiB[0][0], ev0, arB); arB = fdot2(wiB[0][1], ev1, arB);
        arB = fdot2(wiB[0][2], ev2, arB); arB = fdot2(wiB[0][3], ev3, arB);
        arB = fdot2(wiB[0][4], ev4, arB);
        azB = fdot2(wiB[1][0], ev0, azB); azB = fdot2(wiB[1][1], ev1, azB);
        azB = fdot2(wiB[1][2], ev2, azB); azB = fdot2(wiB[1][3], ev3, azB);
        azB = fdot2(wiB[1][4], ev4, azB);
        giB = fdot2(wiB[2][0], ev0, giB); giB = fdot2(wiB[2][1], ev1, giB);
        giB = fdot2(wiB[2][2], ev2, giB); giB = fdot2(wiB[2][3], ev3, giB);
        giB = fdot2(wiB[2][4], ev4, giB);
        arA = fdot2(w96A[0][0], tv0, arA); arA = fdot2(w96A[0][1], tv1, arA);
        azA = fdot2(w96A[1][0], tv0, azA); azA = fdot2(w96A[1][1], tv1, azA);
        ghA = fdot2(w96A[2][0], tv0, ghA); ghA = fdot2(w96A[2][1], tv1, ghA);
        arB = fdot2(w96B[0][0], tv0, arB); arB = fdot2(w96B[0][1], tv1, arB);
        azB = fdot2(w96B[1][0], tv0, azB); azB = fdot2(w96B[1][1], tv1, azB);
        ghB = fdot2(w96B[2][0], tv0, ghB); ghB = fdot2(w96B[2][1], tv1, ghB);

        __syncthreads();   // gates complete (both waves); drains LDS ops

        // gate reads + mix (redundant in both waves; h stays in registers)
        float grA = gpf[uA], gzA = gpf[100 + uA], gnA = gpf[200 + uA];
        float grB = gpf[uB], gzB = gpf[100 + uB], gnB = gpf[200 + uB];

        float r1 = sigm(arA + grA);
        float z1 = sigm(azA + gzA);
        float n1 = tanh_f(giA + r1 * (ghA + gnA));
        hA = n1 + z1 * (hA - n1);

        float r2 = sigm(arB + grB);
        float z2 = sigm(azB + gzB);
        float n2 = tanh_f(giB + r2 * (ghB + gnB));
        float hBn = n2 + z2 * (hB - n2);
        hB = (l < 36) ? hBn : hB;
    }

    // ---- epilogue: sigmoid(relu(h) . fc_w + fc_b) ----
    float acc = fmaxf(hA, 0.f) * fwA + ((l < 36) ? fmaxf(hB, 0.f) * fwB : 0.f);
    #pragma unroll
    for (int k = 32; k >= 1; k >>= 1) acc += __shfl_xor(acc, k, 64);
    if (tid == 0) out[0] = sigm(acc + fc_b[0]);
}

extern "C" void kernel_launch(void* const* d_in, const int* in_sizes, int n_in,
                              void* d_out, int out_size, void* d_ws, size_t ws_size,
                              hipStream_t stream) {
    const int*   x      = (const int*)  d_in[0];
    const float* hidden = (const float*)d_in[1];
    const float* embed  = (const float*)d_in[2];
    const float* w_ih   = (const float*)d_in[3];
    const float* w_hh   = (const float*)d_in[4];
    const float* b_ih   = (const float*)d_in[5];
    const float* b_hh   = (const float*)d_in[6];
    const float* fc_w   = (const float*)d_in[7];
    const float* fc_b   = (const float*)d_in[8];
    float*       out    = (float*)d_out;

    gru_fused<<<1, TPB, 0, stream>>>(x, hidden, embed, w_ih, w_hh,
                                     b_ih, b_hh, fc_w, fc_b, out);
}

// Round 8
// 374.607 us; speedup vs baseline: 2.1859x; 1.6406x over previous
//
#include <hip/hip_runtime.h>

#define SEQ 550
#define MID 100
#define TPB 128

typedef _Float16 half2_t __attribute__((ext_vector_type(2)));
typedef __fp16  fp16x2  __attribute__((ext_vector_type(2)));

union H2I { int i; half2_t h; };
union PKC { fp16x2 p; half2_t h; };
union QI  { int4 v; int s[4]; };

__device__ __forceinline__ float fdot2(half2_t a, half2_t b, float c) {
    return __builtin_amdgcn_fdot2(a, b, c, false);
}
__device__ __forceinline__ float sigm(float x) { return 1.0f / (1.0f + __expf(-x)); }
__device__ __forceinline__ float tanh_f(float x) { return 1.0f - 2.0f / (__expf(2.0f * x) + 1.0f); }
__device__ __forceinline__ half2_t i2h(int v) { H2I u; u.i = v; return u.h; }
// quad_perm [1,0,3,2]: even lane receives odd neighbor's value
__device__ __forceinline__ float pull_odd(float x) {
    int y = __builtin_amdgcn_update_dpp(0, __float_as_int(x), 0xB1, 0xF, 0xF, true);
    return __int_as_float(y);
}
__device__ __forceinline__ int pk2i(float a, float b) {
    PKC u; u.p = __builtin_amdgcn_cvt_pkrtz(a, b); H2I c; c.h = u.h; return c.i;
}

// 2 waves. Wave w owns units [50w, 50w+50). Lane l (<50) owns unit u = 50w+l and
// computes ALL THREE gate rows (r,z,n) of u as full 100-wide dots in-register:
// no cross-lane reduction, no gates buffer. Only h crosses lanes/waves, via a
// 50-dword ping-pong LDS buffer (25 ds_write_b32 per wave, 13 broadcast reads).
// One __syncthreads per step (write buf[t^1], read buf[t] -- r1-validated).

__global__ __launch_bounds__(TPB, 1)
__attribute__((amdgpu_waves_per_eu(1, 1)))
void gru_fused(
    const int*   __restrict__ x,
    const float* __restrict__ hidden,
    const float* __restrict__ embed,
    const float* __restrict__ w_ih,
    const float* __restrict__ w_hh,
    const float* __restrict__ b_ih,
    const float* __restrict__ b_hh,
    const float* __restrict__ fc_w,
    const float* __restrict__ fc_b,
    float*       __restrict__ out)
{
    __shared__ __align__(16) int seqbuf[SEQ * 8];   // e_t: 5 packed half2 + pad, 32B stride
    __shared__ __align__(16) int hb[2][64];         // ping-pong h: dword k = (h[2k],h[2k+1]) fp16
    __shared__ float partial[MID];

    const int tid = threadIdx.x;
    const int w   = tid >> 6;
    const int l   = tid & 63;
    const int lc  = (l < 50) ? l : 49;
    const int u   = 50 * w + lc;            // owned unit (lanes 50..63 duplicate unit 49)

    // ---- stage embedded sequence as fp16 ----
    for (int i = tid; i < SEQ * 5; i += TPB) {
        int t = i / 5, j = i - 5 * t;
        float2 f = *(const float2*)(embed + x[t] * 10 + 2 * j);
        H2I c; c.h = half2_t{(_Float16)f.x, (_Float16)f.y};
        seqbuf[t * 8 + j] = c.i;
    }

    // ---- per-lane weights: 3 full gate rows of unit u (hidden 50 half2 + input 5 half2) ----
    half2_t whh[3][50];
    half2_t wih[3][5];
    #pragma unroll
    for (int r = 0; r < 3; r++) {
        const float* p = w_hh + (r * MID + u) * MID;
        #pragma unroll
        for (int k = 0; k < 25; k++) {
            float4 f = ((const float4*)p)[k];
            whh[r][2 * k]     = half2_t{(_Float16)f.x, (_Float16)f.y};
            whh[r][2 * k + 1] = half2_t{(_Float16)f.z, (_Float16)f.w};
        }
        const float* q = w_ih + (r * MID + u) * 10;
        #pragma unroll
        for (int k = 0; k < 5; k++) {
            float2 f = *(const float2*)(q + 2 * k);
            wih[r][k] = half2_t{(_Float16)f.x, (_Float16)f.y};
        }
    }
    // pin weights in VGPRs (defeat rematerialization; ~165 regs, fits)
    #pragma unroll
    for (int r = 0; r < 3; r++) {
        #pragma unroll
        for (int k = 0; k < 50; k++) asm volatile("" : "+v"(whh[r][k]));
        #pragma unroll
        for (int k = 0; k < 5; k++)  asm volatile("" : "+v"(wih[r][k]));
    }

    const float br  = b_ih[u] + b_hh[u];
    const float bz  = b_ih[MID + u] + b_hh[MID + u];
    const float bin = b_ih[2 * MID + u];
    const float bhn = b_hh[2 * MID + u];

    float hreg = hidden[u];
    const float fcw = fc_w[u];

    // ---- init h buffer 0: even owner lanes write their pair ----
    {
        float ho = pull_odd(hreg);
        if (l < 50 && !(l & 1)) hb[0][25 * w + (l >> 1)] = pk2i(hreg, ho);
    }
    __syncthreads();

    #pragma unroll 1
    for (int t = 0; t < SEQ; t++) {
        const int* rb = hb[t & 1];

        // e_t (broadcast reads, independent of h -> issue first)
        const int* eb = seqbuf + t * 8;
        int4 e4 = *(const int4*)eb;
        int  e1 = eb[4];

        // h: 13 broadcast reads (48 dwords as int4 + 2 dwords)
        QI qa[12];
        const int4* hp = (const int4*)rb;
        #pragma unroll
        for (int j = 0; j < 12; j++) qa[j].v = hp[j];
        int2 qb = ((const int2*)rb)[24];

        // input-side chains (overlap h-read latency)
        half2_t ev0 = i2h(e4.x), ev1 = i2h(e4.y), ev2 = i2h(e4.z), ev3 = i2h(e4.w), ev4 = i2h(e1);
        float arE = 0.f, azE = 0.f, gin = bin;
        arE = fdot2(wih[0][0], ev0, arE); arE = fdot2(wih[0][1], ev1, arE);
        arE = fdot2(wih[0][2], ev2, arE); arE = fdot2(wih[0][3], ev3, arE);
        arE = fdot2(wih[0][4], ev4, arE);
        azE = fdot2(wih[1][0], ev0, azE); azE = fdot2(wih[1][1], ev1, azE);
        azE = fdot2(wih[1][2], ev2, azE); azE = fdot2(wih[1][3], ev3, azE);
        azE = fdot2(wih[1][4], ev4, azE);
        gin = fdot2(wih[2][0], ev0, gin); gin = fdot2(wih[2][1], ev1, gin);
        gin = fdot2(wih[2][2], ev2, gin); gin = fdot2(wih[2][3], ev3, gin);
        gin = fdot2(wih[2][4], ev4, gin);

        // hidden-side: 150 fdot2 in 6 independent chains (2 per gate row)
        float ar = br, az = bz, ghn = bhn;
        float ar2 = 0.f, az2 = 0.f, ghn2 = 0.f;
        #pragma unroll
        for (int k = 0; k < 50; k++) {
            int raw = (k < 48) ? qa[k >> 2].s[k & 3] : ((k == 48) ? qb.x : qb.y);
            half2_t hv = i2h(raw);
            if (k < 25) {
                ar   = fdot2(whh[0][k], hv, ar);
                az   = fdot2(whh[1][k], hv, az);
                ghn  = fdot2(whh[2][k], hv, ghn);
            } else {
                ar2  = fdot2(whh[0][k], hv, ar2);
                az2  = fdot2(whh[1][k], hv, az2);
                ghn2 = fdot2(whh[2][k], hv, ghn2);
            }
        }

        // mix (fp32 state, fully in-register)
        float R = sigm((ar + ar2) + arE);
        float Z = sigm((az + az2) + azE);
        float N = tanh_f(gin + R * (ghn + ghn2));
        hreg = N + Z * (hreg - N);

        // publish h pair (even owner lanes) into the other buffer
        float ho = pull_odd(hreg);
        if (l < 50 && !(l & 1)) hb[(t & 1) ^ 1][25 * w + (l >> 1)] = pk2i(hreg, ho);

        __syncthreads();   // single 2-wave barrier per step
    }

    // ---- epilogue: sigmoid(relu(h) . fc_w + fc_b) ----
    if (l < 50) partial[u] = fmaxf(hreg, 0.f) * fcw;
    __syncthreads();
    if (tid == 0) {
        float s = fc_b[0];
        const float4* pp = (const float4*)partial;
        #pragma unroll
        for (int k = 0; k < 25; k++) {
            float4 f = pp[k];
            s += (f.x + f.y) + (f.z + f.w);
        }
        out[0] = sigm(s);
    }
}

extern "C" void kernel_launch(void* const* d_in, const int* in_sizes, int n_in,
                              void* d_out, int out_size, void* d_ws, size_t ws_size,
                              hipStream_t stream) {
    const int*   x      = (const int*)  d_in[0];
    const float* hidden = (const float*)d_in[1];
    const float* embed  = (const float*)d_in[2];
    const float* w_ih   = (const float*)d_in[3];
    const float* w_hh   = (const float*)d_in[4];
    const float* b_ih   = (const float*)d_in[5];
    const float* b_hh   = (const float*)d_in[6];
    const float* fc_w   = (const float*)d_in[7];
    const float* fc_b   = (const float*)d_in[8];
    float*       out    = (float*)d_out;

    gru_fused<<<1, TPB, 0, stream>>>(x, hidden, embed, w_ih, w_hh,
                                     b_ih, b_hh, fc_w, fc_b, out);
}

// Round 9
// 312.871 us; speedup vs baseline: 2.6173x; 1.1973x over previous
//
#include <hip/hip_runtime.h>

#define SEQ 550
#define MID 100
#define TPB 256

typedef _Float16 half2_t __attribute__((ext_vector_type(2)));

union H2I { int i; half2_t h; ushort2 u2; };
union QI  { int4 v; int s[4]; };

__device__ __forceinline__ float fdot2(half2_t a, half2_t b, float c) {
    return __builtin_amdgcn_fdot2(a, b, c, false);
}
__device__ __forceinline__ float sigm(float x) { return 1.0f / (1.0f + __expf(-x)); }
__device__ __forceinline__ float tanh_f(float x) { return 1.0f - 2.0f / (__expf(2.0f * x) + 1.0f); }
__device__ __forceinline__ half2_t i2h(int v) { H2I u; u.i = v; return u.h; }

// sum of adjacent lane pair via DPP quad_perm [1,0,3,2] — VALU only, no LDS
__device__ __forceinline__ float pair_sum(float x) {
    int yi = __builtin_amdgcn_update_dpp(0, __float_as_int(x), 0xB1, 0xF, 0xF, true);
    return x + __int_as_float(yi);
}

// r1 structure (240us) + TRUE weight residency:
//   pair (2u, 2u+1) owns unit u; p = tid&1 takes h-cols [50p,50p+50) + its emb slice.
//   Weights are cvt'd to fp16 ONCE and pinned via asm "+v", loaded in batches of 5
//   with sched_barrier(0) fences so init-phase register pressure never exceeds the
//   budget (r8 lesson: a pressure spike at init poisons the whole loop with spills).
//   One __syncthreads per step; ping-pong fp16 h buffer; DPP pair-sum; fp32 state.

__global__ __launch_bounds__(TPB, 1)
__attribute__((amdgpu_waves_per_eu(1, 1)))
void gru_fused(
    const int*   __restrict__ x,
    const float* __restrict__ hidden,
    const float* __restrict__ embed,
    const float* __restrict__ w_ih,
    const float* __restrict__ w_hh,
    const float* __restrict__ b_ih,
    const float* __restrict__ b_hh,
    const float* __restrict__ fc_w,
    const float* __restrict__ fc_b,
    float*       __restrict__ out)
{
    // per t: 16 ushorts (32B): halves 0..5 at slots 0..5 (p0), 6..9 at slots 8..11 (p1),
    // slots 12..13 zeroed (hit only by p1's zero weight), 6..7,14..15 never used.
    __shared__ __align__(16) ushort seqbuf[SEQ * 16];   // 17.6 KB
    // ping-pong h: 2 x 256B; within a buffer: p0 halves h[0..49] at [0,100)B, p1 at [128,228)B
    __shared__ __align__(16) int hbuf[128];
    __shared__ float partial[MID];

    const int  tid = threadIdx.x;
    const bool act = tid < 2 * MID;   // 200 workers
    const int  u   = act ? (tid >> 1) : 99;
    const int  p   = tid & 1;
    const int  hidx = (u < 50) ? u : u + 14;   // ushort index within one h buffer

    // ---- stage embedded sequence as fp16 ----
    for (int i = tid; i < SEQ * 10; i += TPB) {
        int t = i / 10;
        int k = i - 10 * t;
        H2I c; c.h = half2_t{(_Float16)embed[x[t] * 10 + k], (_Float16)0.0f};
        seqbuf[t * 16 + (k < 6 ? k : k + 2)] = c.u2.x;
    }
    for (int i = tid; i < SEQ; i += TPB)
        *(int*)(seqbuf + i * 16 + 12) = 0;   // zero the pad slots p1's third fdot2 touches

    // ---- per-thread weights, pinned resident (batched cvt + sched_barrier fences) ----
    half2_t whh[3][25];
    half2_t wihr[3][3];
    float b0 = 0.f, b1 = 0.f, b2 = 0.f, b3 = 0.f, hreg = 0.f, fcw = 0.f;

    if (act) {
        #pragma unroll
        for (int r = 0; r < 3; r++) {
            const float2* wr = (const float2*)(w_hh + (r * MID + u) * MID) + 25 * p;
            #pragma unroll
            for (int k = 0; k < 25; k++) {
                float2 f = wr[k];
                whh[r][k] = half2_t{(_Float16)f.x, (_Float16)f.y};
                asm volatile("" : "+v"(whh[r][k]));
                if ((k % 5) == 4) __builtin_amdgcn_sched_barrier(0);
            }
            const float* wi = w_ih + (r * MID + u) * 10 + 6 * p;
            wihr[r][0] = half2_t{(_Float16)wi[0], (_Float16)wi[1]};
            wihr[r][1] = half2_t{(_Float16)wi[2], (_Float16)wi[3]};
            if (p == 0) wihr[r][2] = half2_t{(_Float16)wi[4], (_Float16)wi[5]};
            else        wihr[r][2] = half2_t{(_Float16)0.f, (_Float16)0.f};
            asm volatile("" : "+v"(wihr[r][0]), "+v"(wihr[r][1]), "+v"(wihr[r][2]));
            __builtin_amdgcn_sched_barrier(0);
        }
        if (p == 0) {                         // biases counted once per pair
            b0 = b_ih[u]           + b_hh[u];
            b1 = b_ih[MID + u]     + b_hh[MID + u];
            b2 = b_ih[2 * MID + u];           // input side of n-gate
            b3 = b_hh[2 * MID + u];           // hidden side of n-gate (r-scaled)
        }
        hreg = hidden[u];
        fcw  = fc_w[u];
        if (p == 0) ((_Float16*)hbuf)[hidx] = (_Float16)hreg;   // init buffer 0
    }
    float fcb = (tid == 0) ? fc_b[0] : 0.0f;

    __syncthreads();

    #pragma unroll 1
    for (int t = 0; t < SEQ; t++) {
        if (act) {
            // ---- my half of h: 2 broadcast addresses per ds_read, conflict-free ----
            const int   rbase = ((t & 1) << 8) + (p << 7);           // byte offset
            const int4* hp4   = (const int4*)((const char*)hbuf + rbase);
            QI q0, q1, q2, q3, q4, q5;
            q0.v = hp4[0]; q1.v = hp4[1]; q2.v = hp4[2];
            q3.v = hp4[3]; q4.v = hp4[4]; q5.v = hp4[5];
            int  qe = ((const int*)hp4)[24];
            int4 ev = *(const int4*)(seqbuf + t * 16 + p * 8);       // my emb slice

            half2_t hh[25];
            hh[0]=i2h(q0.s[0]);  hh[1]=i2h(q0.s[1]);  hh[2]=i2h(q0.s[2]);  hh[3]=i2h(q0.s[3]);
            hh[4]=i2h(q1.s[0]);  hh[5]=i2h(q1.s[1]);  hh[6]=i2h(q1.s[2]);  hh[7]=i2h(q1.s[3]);
            hh[8]=i2h(q2.s[0]);  hh[9]=i2h(q2.s[1]);  hh[10]=i2h(q2.s[2]); hh[11]=i2h(q2.s[3]);
            hh[12]=i2h(q3.s[0]); hh[13]=i2h(q3.s[1]); hh[14]=i2h(q3.s[2]); hh[15]=i2h(q3.s[3]);
            hh[16]=i2h(q4.s[0]); hh[17]=i2h(q4.s[1]); hh[18]=i2h(q4.s[2]); hh[19]=i2h(q4.s[3]);
            hh[20]=i2h(q5.s[0]); hh[21]=i2h(q5.s[1]); hh[22]=i2h(q5.s[2]); hh[23]=i2h(q5.s[3]);
            hh[24]=i2h(qe);

            // ---- half-dots for the 3 gate rows of my unit ----
            float s0 = b0, s1 = b1, s2 = b2, s3 = b3;
            #pragma unroll
            for (int k = 0; k < 25; k++) {
                half2_t hv = hh[k];
                s0 = fdot2(whh[0][k], hv, s0);   // r row (hidden)
                s1 = fdot2(whh[1][k], hv, s1);   // z row (hidden)
                s3 = fdot2(whh[2][k], hv, s3);   // n row (hidden, kept separate for r-scale)
            }
            half2_t e0 = i2h(ev.x), e1 = i2h(ev.y), e2 = i2h(ev.z);
            s0 = fdot2(wihr[0][0], e0, s0); s0 = fdot2(wihr[0][1], e1, s0); s0 = fdot2(wihr[0][2], e2, s0);
            s1 = fdot2(wihr[1][0], e0, s1); s1 = fdot2(wihr[1][1], e1, s1); s1 = fdot2(wihr[1][2], e2, s1);
            s2 = fdot2(wihr[2][0], e0, s2); s2 = fdot2(wihr[2][1], e1, s2); s2 = fdot2(wihr[2][2], e2, s2);

            // ---- combine pair halves in-register ----
            float ar  = pair_sum(s0);
            float az  = pair_sum(s1);
            float gin = pair_sum(s2);
            float ghn = pair_sum(s3);

            float r = sigm(ar);
            float z = sigm(az);
            float n = tanh_f(gin + r * ghn);
            hreg = n + z * (hreg - n);              // exact fp32 state
            if (p == 0)
                ((_Float16*)hbuf)[(((t & 1) ^ 1) << 7) + hidx] = (_Float16)hreg;
        }
        __syncthreads();   // single barrier per step; ping-pong makes it race-free
    }

    // ---- epilogue: sigmoid(relu(h) . fc_w + fc_b) ----
    if (act && p == 0) partial[u] = fmaxf(hreg, 0.0f) * fcw;
    __syncthreads();
    if (tid == 0) {
        float s = fcb;
        const float4* pp = (const float4*)partial;
        #pragma unroll
        for (int k = 0; k < 25; k++) {
            float4 f = pp[k];
            s += (f.x + f.y) + (f.z + f.w);
        }
        out[0] = sigm(s);
    }
}

extern "C" void kernel_launch(void* const* d_in, const int* in_sizes, int n_in,
                              void* d_out, int out_size, void* d_ws, size_t ws_size,
                              hipStream_t stream) {
    const int*   x      = (const int*)  d_in[0];
    const float* hidden = (const float*)d_in[1];
    const float* embed  = (const float*)d_in[2];
    const float* w_ih   = (const float*)d_in[3];
    const float* w_hh   = (const float*)d_in[4];
    const float* b_ih   = (const float*)d_in[5];
    const float* b_hh   = (const float*)d_in[6];
    const float* fc_w   = (const float*)d_in[7];
    const float* fc_b   = (const float*)d_in[8];
    float*       out    = (float*)d_out;

    gru_fused<<<1, TPB, 0, stream>>>(x, hidden, embed, w_ih, w_hh,
                                     b_ih, b_hh, fc_w, fc_b, out);
}